// Round 1
// baseline (532.847 us; speedup 1.0000x reference)
//
#include <hip/hip_runtime.h>

// ASG loss, B=128 T=4000 N=64 L=101.
// Strategy: forward/backward split at T/2 -> 256 independent chains (one WG/CU).
// Denominator recurrence run in LINEAR space with per-step rescale:
//   P_j = 2^(alpha_j - C);  S_i = sum_j W_ij * P_j  (pure FMA, W=2^w in regs)
//   P'_i = S_i * rcp(P0) * 2^(e_i*log2e);  C += log2(P0)
// Numerator (101-state chain) in log2 domain in 2 extra waves of the same WG.
// Hot loop uses raw s_barrier + lgkmcnt(0) only (no vmcnt drain) so the
// 4-step-deep emission prefetch stays in flight across barriers.

#define TT 4000
#define NN 64
#define LL 101

static constexpr float L2E  = 1.44269504088896340736f;   // log2(e)
static constexpr float LN2F = 0.69314718055994530942f;
static constexpr float NEG2 = -1.0e30f;

// ws layout (floats):
#define WS_AF   0         // [128][64] forward alpha (log2) at t=1999
#define WS_GB   8192      // [128][64] backward g    (log2) at t=2000
#define WS_NF   16384     // [128][112] forward numer nbeta (log2) at t=1999
#define WS_HB   30720     // [128][112] backward numer h   (log2) at t=2000
#define WS_LOSS 45056     // [128] per-batch loss

__global__ __launch_bounds__(384) void asg_main(
    const float* __restrict__ E, const float* __restrict__ TR,
    const int* __restrict__ Y, float* __restrict__ ws)
{
  const int b   = blockIdx.x >> 1;
  const int dir = blockIdx.x & 1;            // 0 = forward, 1 = backward
  const float* eb = E + (size_t)b * TT * NN;

  __shared__ float P[2][NN];                 // denom linear state (double buf)
  __shared__ float NB[2][104];               // numer log2 state  (double buf)

  const int tid = threadIdx.x;

  if (tid < 256) {
    // ---------------- denominator waves (0..3) ----------------
    const int i  = tid >> 2;                 // output state 0..63
    const int jg = tid & 3;                  // j-slice 16*jg..16*jg+15
    float W[16];
#pragma unroll
    for (int k = 0; k < 16; ++k) {
      const int jj = jg * 16 + k;
      const float w = (dir == 0) ? TR[(i + 1) * NN + jj]   // w[i][j]
                                 : TR[(jj + 1) * NN + i];  // w^T[i][j] = w[j][i]
      W[k] = exp2f(w * L2E);
    }
    float a0;
    if (dir == 0) a0 = (eb[i] + TR[i]) * L2E;                 // e(0,i)+init
    else          a0 = eb[(size_t)(TT - 1) * NN + i] * L2E;   // e(T-1,i)
    if (jg == 0) P[1][i] = a0;
    __syncthreads();
    const float A00 = P[1][0];
    float Csum = A00;
    float Pl = exp2f(a0 - A00);
    if (jg == 0) P[0][i] = Pl;
    __syncthreads();

    const float* ebase = eb + i;
    // emission row for step s: fwd row=s, bwd row=T-1-s
#define EADDR(s) (ebase + (size_t)((dir == 0) ? (s) : (TT - 1 - (s))) * NN)

    float e0 = *EADDR(1), e1 = *EADDR(2), e2 = *EADDR(3), e3 = *EADDR(4);
    int buf = 0;

#define DSTEP(EC)                                                              \
    {                                                                          \
      const float4* pv = (const float4*)&P[buf][jg * 16];                      \
      const float4 q0 = pv[0], q1 = pv[1], q2 = pv[2], q3 = pv[3];             \
      const float P0 = P[buf][0];                                              \
      float sa = fmaf(q0.y, W[1], q0.x * W[0]);                                \
      sa = fmaf(q0.z, W[2], sa); sa = fmaf(q0.w, W[3], sa);                    \
      float sb = fmaf(q1.y, W[5], q1.x * W[4]);                                \
      sb = fmaf(q1.z, W[6], sb); sb = fmaf(q1.w, W[7], sb);                    \
      float sc = fmaf(q2.y, W[9], q2.x * W[8]);                                \
      sc = fmaf(q2.z, W[10], sc); sc = fmaf(q2.w, W[11], sc);                  \
      float sd = fmaf(q3.y, W[13], q3.x * W[12]);                              \
      sd = fmaf(q3.z, W[14], sd); sd = fmaf(q3.w, W[15], sd);                  \
      float S = (sa + sb) + (sc + sd);                                         \
      S += __shfl_xor(S, 1);                                                   \
      S += __shfl_xor(S, 2);                                                   \
      Pl = S * __builtin_amdgcn_rcpf(P0) * exp2f((EC) * L2E);                  \
      Csum += log2f(P0);                                                       \
      if (jg == 0) P[buf ^ 1][i] = Pl;                                         \
      asm volatile("s_waitcnt lgkmcnt(0)" ::: "memory");                       \
      __builtin_amdgcn_s_barrier();                                            \
      asm volatile("" ::: "memory");                                           \
      buf ^= 1;                                                                \
    }

    for (int it = 0; it < 499; ++it) {       // steps 1..1996
      const int s = 1 + it * 4;
      const float t0 = e0, t1 = e1, t2 = e2, t3 = e3;
      e0 = *EADDR(s + 4); DSTEP(t0);
      e1 = *EADDR(s + 5); DSTEP(t1);
      e2 = *EADDR(s + 6); DSTEP(t2);
      e3 = *EADDR(s + 7); DSTEP(t3);
    }
    DSTEP(e0);                               // steps 1997..1999
    DSTEP(e1);
    DSTEP(e2);
#undef DSTEP
#undef EADDR

    if (jg == 0)
      ws[(dir ? WS_GB : WS_AF) + b * NN + i] = Csum + log2f(Pl);

  } else {
    // ---------------- numerator waves (4..5) ----------------
    const int l = tid - 256;                 // 0..127
    const bool act = (l < LL);
    const int lc = act ? l : (LL - 1);
    const int y  = Y[b * LL + lc];
    const int ym = Y[b * LL + (lc > 0 ? lc - 1 : 0)];
    const int yp = Y[b * LL + (lc < LL - 1 ? lc + 1 : LL - 1)];
    const float stw = TR[(y + 1) * NN + y] * L2E;
    float advw, nb;
    if (dir == 0) {
      advw = TR[(y + 1) * NN + ym] * L2E;                 // y_{l-1} -> y_l
      const float ey0 = eb[y] * L2E;
      nb = (l == 0) ? (TR[y] * L2E + ey0) : NEG2;
    } else {
      advw = TR[(yp + 1) * NN + y] * L2E;                 // y_l -> y_{l+1}
      const float ey0 = eb[(size_t)(TT - 1) * NN + y] * L2E;
      nb = ey0 + ((l == LL - 1) ? 0.f : NEG2);
    }
    __syncthreads();
    if (act) NB[0][l] = nb;
    __syncthreads();

#define EYADDR(s) (eb + (size_t)((dir == 0) ? (s) : (TT - 1 - (s))) * NN + y)
    float e0 = *EYADDR(1), e1 = *EYADDR(2), e2 = *EYADDR(3), e3 = *EYADDR(4);
    int buf = 0;
    const bool rdok = act && ((dir == 0) ? (l > 0) : (l < LL - 1));
    const int nbr = (dir == 0) ? (l - 1) : (l + 1);

#define NSTEP(EC)                                                              \
    {                                                                          \
      const float nbh = rdok ? NB[buf][nbr] : NEG2;                            \
      const float s1 = nb + stw;                                               \
      const float s2 = nbh + advw;                                             \
      const float m = fmaxf(s1, s2);                                           \
      nb = m + log2f(exp2f(s1 - m) + exp2f(s2 - m)) + (EC) * L2E;              \
      if (act) NB[buf ^ 1][l] = nb;                                            \
      asm volatile("s_waitcnt lgkmcnt(0)" ::: "memory");                       \
      __builtin_amdgcn_s_barrier();                                            \
      asm volatile("" ::: "memory");                                           \
      buf ^= 1;                                                                \
    }

    for (int it = 0; it < 499; ++it) {
      const int s = 1 + it * 4;
      const float t0 = e0, t1 = e1, t2 = e2, t3 = e3;
      e0 = *EYADDR(s + 4); NSTEP(t0);
      e1 = *EYADDR(s + 5); NSTEP(t1);
      e2 = *EYADDR(s + 6); NSTEP(t2);
      e3 = *EYADDR(s + 7); NSTEP(t3);
    }
    NSTEP(e0);
    NSTEP(e1);
    NSTEP(e2);
#undef NSTEP
#undef EYADDR

    if (act) ws[(dir ? WS_HB : WS_NF) + b * 112 + l] = nb;
  }
}

__global__ __launch_bounds__(128) void asg_combine(
    const float* __restrict__ TR, const int* __restrict__ Y,
    const float* __restrict__ ws, float* __restrict__ lossv)
{
  const int b = blockIdx.x;
  const int tid = threadIdx.x;
  __shared__ float sA[NN], sG[NN], sN[LL], sH[LL], red[128];
  __shared__ float sLogZ;
  if (tid < NN) { sA[tid] = ws[WS_AF + b * NN + tid]; sG[tid] = ws[WS_GB + b * NN + tid]; }
  if (tid < LL) { sN[tid] = ws[WS_NF + b * 112 + tid]; sH[tid] = ws[WS_HB + b * 112 + tid]; }
  __syncthreads();

  // bridge denominator: alpha'[i] = LSE2_j(w[i][j] + alpha_1999[j]); val = alpha' + g_2000
  float val = -3.0e38f;
  if (tid < NN) {
    const int i = tid;
    float m = -3.0e38f;
    for (int j = 0; j < NN; ++j) m = fmaxf(m, sA[j] + TR[(i + 1) * NN + j] * L2E);
    float s = 0.f;
    for (int j = 0; j < NN; ++j) s += exp2f(sA[j] + TR[(i + 1) * NN + j] * L2E - m);
    val = m + log2f(s) + sG[i];
  }
  red[tid] = val;
  __syncthreads();
  if (tid == 0) {
    float m = red[0];
    for (int k = 1; k < NN; ++k) m = fmaxf(m, red[k]);
    float s = 0.f;
    for (int k = 0; k < NN; ++k) s += exp2f(red[k] - m);
    sLogZ = m + log2f(s);
  }
  __syncthreads();

  // bridge numerator: nbeta'[l] = LSE2(nF[l]+stay, nF[l-1]+adv); val = nbeta' + h
  float val2 = -3.0e38f;
  if (tid < LL) {
    const int l = tid;
    const int y = Y[b * LL + l];
    const float s1 = sN[l] + TR[(y + 1) * NN + y] * L2E;
    float s2 = NEG2;
    if (l > 0) {
      const int ymm = Y[b * LL + l - 1];
      s2 = sN[l - 1] + TR[(y + 1) * NN + ymm] * L2E;
    }
    const float m = fmaxf(s1, s2);
    val2 = m + log2f(exp2f(s1 - m) + exp2f(s2 - m)) + sH[l];
  }
  red[tid] = val2;
  __syncthreads();
  if (tid == 0) {
    float m = red[0];
    for (int k = 1; k < LL; ++k) m = fmaxf(m, red[k]);
    float s = 0.f;
    for (int k = 0; k < LL; ++k) s += exp2f(red[k] - m);
    const float tgt2 = m + log2f(s);
    lossv[b] = (sLogZ - tgt2) * LN2F / (float)LL;
  }
}

__global__ __launch_bounds__(64) void asg_reduce(const float* __restrict__ lossv,
                                                 float* __restrict__ out)
{
  const int tid = threadIdx.x;
  float v = lossv[tid] + lossv[tid + 64];
  for (int off = 32; off; off >>= 1) v += __shfl_xor(v, off);
  if (tid == 0) out[0] = v * (1.0f / 128.0f);
}

extern "C" void kernel_launch(void* const* d_in, const int* in_sizes, int n_in,
                              void* d_out, int out_size, void* d_ws, size_t ws_size,
                              hipStream_t stream) {
  const float* E  = (const float*)d_in[0];
  const float* TR = (const float*)d_in[1];
  const int*   Y  = (const int*)d_in[2];
  float* out = (float*)d_out;
  float* ws  = (float*)d_ws;
  float* lossv = ws + WS_LOSS;

  asg_main<<<dim3(256), dim3(384), 0, stream>>>(E, TR, Y, ws);
  asg_combine<<<dim3(128), dim3(128), 0, stream>>>(TR, Y, ws, lossv);
  asg_reduce<<<dim3(1), dim3(64), 0, stream>>>(lossv, out);
}

// Round 2
// 444.872 us; speedup vs baseline: 1.1978x; 1.1978x over previous
//
#include <hip/hip_runtime.h>

// ASG loss, B=128 T=4000 N=64 L=101.
// R2: barrier-free single-wave recurrences.
//  - Denominator: 1 wave per (batch,dir); lane i = state i. State vector in
//    LDS (fp16 if v_dot2_f32_f16 available, else f32 pair-split). Same-wave
//    LDS ops are processed in order -> no s_barrier, no syncthreads.
//  - Numerator: wave 1 of the same block; 2 chain states per lane, one
//    shfl_up/down per step, no LDS.
//  - Emissions prefetched 8 steps deep (named regs, unroll-8 loop).

#define TT 4000
#define NN 64
#define LL 101

static constexpr float L2E  = 1.44269504088896340736f;   // log2(e)
static constexpr float LN2F = 0.69314718055994530942f;
static constexpr float NEG2 = -1.0e30f;

// ws layout (floats):
#define WS_AF   0         // [128][64] forward alpha (log2) at t=1999
#define WS_GB   8192      // [128][64] backward g    (log2) at t=2000
#define WS_NF   16384     // [128][112] forward numer (log2) at t=1999
#define WS_HB   30720     // [128][112] backward numer (log2) at t=2000
#define WS_LOSS 45056     // [128] per-batch loss

#if defined(__has_builtin)
#if __has_builtin(__builtin_amdgcn_fdot2)
#define USE_FDOT2 1
#endif
#endif
#ifndef USE_FDOT2
#define USE_FDOT2 0
#endif

typedef _Float16 h2 __attribute__((ext_vector_type(2)));

__global__ __launch_bounds__(128) void asg_main(
    const float* __restrict__ E, const float* __restrict__ TR,
    const int* __restrict__ Y, float* __restrict__ ws)
{
  const int b   = blockIdx.x >> 1;
  const int dir = blockIdx.x & 1;            // 0 = forward, 1 = backward
  const float* em = E + (size_t)b * TT * NN;
  const int tid  = threadIdx.x;
  const int wid  = tid >> 6;
  const int lane = tid & 63;

#if USE_FDOT2
  __shared__ _Float16 PS[2][64];
#else
  __shared__ float PS[2][64];
#endif

  if (wid == 0) {
    // ================= denominator wave =================
    const int i = lane;
#if USE_FDOT2
    h2 W2[32];
#pragma unroll
    for (int k = 0; k < 32; ++k) {
      const float w0 = (dir == 0) ? TR[(i + 1) * NN + 2 * k]     : TR[(2 * k + 1) * NN + i];
      const float w1 = (dir == 0) ? TR[(i + 1) * NN + 2 * k + 1] : TR[(2 * k + 2) * NN + i];
      h2 t; t.x = (_Float16)exp2f(w0 * L2E); t.y = (_Float16)exp2f(w1 * L2E);
      W2[k] = t;
    }
#else
    // pair-split: lane i handles states {i, i^32} over j-half [h0, h0+32)
    const int h0 = (i >> 5) << 5;
    const int ip = i ^ 32;
    float WA[32], WB[32];
#pragma unroll
    for (int k = 0; k < 32; ++k) {
      const int j = h0 + k;
      const float wa = (dir == 0) ? TR[(i + 1) * NN + j]  : TR[(j + 1) * NN + i];
      const float wb = (dir == 0) ? TR[(ip + 1) * NN + j] : TR[(j + 1) * NN + ip];
      WA[k] = exp2f(wa * L2E);
      WB[k] = exp2f(wb * L2E);
    }
#endif
    float a0 = (dir == 0) ? (em[i] + TR[i]) * L2E
                          : em[(size_t)(TT - 1) * NN + i] * L2E;
    const float a00 = __shfl(a0, 0);
    float Csum = a00;
    float Pl = exp2f(a0 - a00);
#if USE_FDOT2
    PS[0][i] = (_Float16)Pl;
#else
    PS[0][i] = Pl;
#endif
    asm volatile("" ::: "memory");

    const float* ebase = em + i;
#define EROW(s) ((size_t)((dir == 0) ? (s) : (TT - 1 - (s))) * NN)
#define ELD(s)  ebase[EROW(s)]

    int buf = 0;

#if USE_FDOT2
#define BCH2(x) __builtin_bit_cast(h2, (x))
#define D4(u, k)                                                               \
    c0 = __builtin_amdgcn_fdot2(BCH2(u.x), W2[k], c0, false);                  \
    c1 = __builtin_amdgcn_fdot2(BCH2(u.y), W2[k + 1], c1, false);              \
    c2 = __builtin_amdgcn_fdot2(BCH2(u.z), W2[k + 2], c2, false);              \
    c3 = __builtin_amdgcn_fdot2(BCH2(u.w), W2[k + 3], c3, false);

#define DSTEP(EC)                                                              \
    {                                                                          \
      const uint4* pv = (const uint4*)&PS[buf][0];                             \
      const uint4 u0 = pv[0], u1 = pv[1], u2 = pv[2], u3 = pv[3];              \
      const uint4 u4 = pv[4], u5 = pv[5], u6 = pv[6], u7 = pv[7];              \
      float c0 = 0.f, c1 = 0.f, c2 = 0.f, c3 = 0.f;                            \
      D4(u0, 0)  D4(u1, 4)  D4(u2, 8)  D4(u3, 12)                              \
      D4(u4, 16) D4(u5, 20) D4(u6, 24) D4(u7, 28)                              \
      const float P0 = (float)BCH2(u0.x).x;                                    \
      const float S = (c0 + c1) + (c2 + c3);                                   \
      Pl = S * __builtin_amdgcn_rcpf(P0) * exp2f(fmaf((EC), L2E, -6.f));       \
      Csum += log2f(P0) + 6.f;                                                 \
      PS[buf ^ 1][i] = (_Float16)fminf(Pl, 60000.f);                           \
      asm volatile("" ::: "memory");                                           \
      buf ^= 1;                                                                \
    }
#else
#define F4(q, W_, k, acc)                                                      \
    acc = fmaf(q.x, W_[k], acc);     acc = fmaf(q.y, W_[k + 1], acc);          \
    acc = fmaf(q.z, W_[k + 2], acc); acc = fmaf(q.w, W_[k + 3], acc);

#define DSTEP(EC)                                                              \
    {                                                                          \
      const float4* pv = (const float4*)&PS[buf][h0];                          \
      const float4 q0 = pv[0], q1 = pv[1], q2 = pv[2], q3 = pv[3];             \
      const float4 q4 = pv[4], q5 = pv[5], q6 = pv[6], q7 = pv[7];             \
      const float P0 = PS[buf][0];                                             \
      float a0_ = 0.f, a1_ = 0.f, a2_ = 0.f, a3_ = 0.f;                        \
      float b0_ = 0.f, b1_ = 0.f, b2_ = 0.f, b3_ = 0.f;                        \
      F4(q0, WA, 0, a0_)  F4(q1, WA, 4, a1_)                                   \
      F4(q2, WA, 8, a2_)  F4(q3, WA, 12, a3_)                                  \
      F4(q4, WA, 16, a0_) F4(q5, WA, 20, a1_)                                  \
      F4(q6, WA, 24, a2_) F4(q7, WA, 28, a3_)                                  \
      F4(q0, WB, 0, b0_)  F4(q1, WB, 4, b1_)                                   \
      F4(q2, WB, 8, b2_)  F4(q3, WB, 12, b3_)                                  \
      F4(q4, WB, 16, b0_) F4(q5, WB, 20, b1_)                                  \
      F4(q6, WB, 24, b2_) F4(q7, WB, 28, b3_)                                  \
      const float SA = (a0_ + a1_) + (a2_ + a3_);                              \
      const float SB = (b0_ + b1_) + (b2_ + b3_);                              \
      const float S = SA + __shfl_xor(SB, 32);                                 \
      Pl = S * __builtin_amdgcn_rcpf(P0) * exp2f(fmaf((EC), L2E, -6.f));       \
      Csum += log2f(P0) + 6.f;                                                 \
      PS[buf ^ 1][i] = Pl;                                                     \
      asm volatile("" ::: "memory");                                           \
      buf ^= 1;                                                                \
    }
#endif

    float e0 = ELD(1), e1 = ELD(2), e2 = ELD(3), e3 = ELD(4);
    float e4 = ELD(5), e5 = ELD(6), e6 = ELD(7), e7 = ELD(8);

    for (int it = 0; it < 249; ++it) {       // steps 1..1992
      const int s = 1 + it * 8;
      const float t0 = e0, t1 = e1, t2 = e2, t3 = e3;
      const float t4 = e4, t5 = e5, t6 = e6, t7 = e7;
      e0 = ELD(s + 8);  DSTEP(t0);
      e1 = ELD(s + 9);  DSTEP(t1);
      e2 = ELD(s + 10); DSTEP(t2);
      e3 = ELD(s + 11); DSTEP(t3);
      e4 = ELD(s + 12); DSTEP(t4);
      e5 = ELD(s + 13); DSTEP(t5);
      e6 = ELD(s + 14); DSTEP(t6);
      e7 = ELD(s + 15); DSTEP(t7);
    }
    DSTEP(e0); DSTEP(e1); DSTEP(e2); DSTEP(e3);   // steps 1993..1999
    DSTEP(e4); DSTEP(e5); DSTEP(e6);
#undef DSTEP
#undef ELD
#undef EROW

    ws[(dir ? WS_GB : WS_AF) + b * NN + i] = Csum + log2f(Pl);

  } else {
    // ================= numerator wave =================
    const int l = lane;
    const bool v0 = (2 * l     <= 100);
    const bool v1 = (2 * l + 1 <= 100);
    const int k0 = v0 ? 2 * l     : 100;
    const int k1 = v1 ? 2 * l + 1 : 100;
    const int y0 = Y[b * LL + k0];
    const int y1 = Y[b * LL + k1];
    const float stw0 = TR[(y0 + 1) * NN + y0] * L2E;
    const float stw1 = TR[(y1 + 1) * NN + y1] * L2E;
    float aw0, aw1, b0, b1;
    if (dir == 0) {
      const int ym0 = Y[b * LL + (k0 > 0 ? k0 - 1 : 0)];
      aw0 = TR[(y0 + 1) * NN + ym0] * L2E;            // k0-1 -> k0
      aw1 = TR[(y1 + 1) * NN + y0] * L2E;             // k0   -> k1
      b0 = (k0 == 0) ? (TR[y0] + em[y0]) * L2E : NEG2;
      b1 = NEG2;
    } else {
      aw0 = TR[(y1 + 1) * NN + y0] * L2E;             // k0 -> k0+1(=k1)
      const int kp = (2 * l + 2 <= 100) ? 2 * l + 2 : 100;
      const int yp1 = Y[b * LL + kp];
      aw1 = TR[(yp1 + 1) * NN + y1] * L2E;            // k1 -> k1+1
      b0 = em[(size_t)(TT - 1) * NN + y0] * L2E + ((k0 == 100) ? 0.f : NEG2);
      b1 = em[(size_t)(TT - 1) * NN + y1] * L2E + ((k1 == 100) ? 0.f : NEG2);
    }
    const bool pm0 = (dir == 0) ? (k0 > 0) : v1;
    const bool pm1 = (dir == 0) ? true : (2 * l + 2 <= 100);

#define NROW(s) ((size_t)((dir == 0) ? (s) : (TT - 1 - (s))) * NN)

#define NSTEP(EA, EB)                                                          \
    {                                                                          \
      const float ob0 = b0, ob1 = b1;                                          \
      const float nb = (dir == 0) ? __shfl_up(ob1, 1) : __shfl_down(ob0, 1);   \
      const float p0 = pm0 ? ((dir == 0) ? nb : ob1) + aw0 : NEG2;             \
      const float p1 = pm1 ? ((dir == 0) ? ob0 : nb) + aw1 : NEG2;             \
      const float x0 = ob0 + stw0, x1 = ob1 + stw1;                            \
      const float m0 = fmaxf(x0, p0), m1 = fmaxf(x1, p1);                      \
      b0 = m0 + log2f(exp2f(x0 - m0) + exp2f(p0 - m0)) + (EA) * L2E;           \
      b1 = m1 + log2f(exp2f(x1 - m1) + exp2f(p1 - m1)) + (EB) * L2E;           \
    }

    float ea0 = em[NROW(1) + y0], eb0 = em[NROW(1) + y1];
    float ea1 = em[NROW(2) + y0], eb1 = em[NROW(2) + y1];
    float ea2 = em[NROW(3) + y0], eb2 = em[NROW(3) + y1];
    float ea3 = em[NROW(4) + y0], eb3 = em[NROW(4) + y1];
    float ea4 = em[NROW(5) + y0], eb4 = em[NROW(5) + y1];
    float ea5 = em[NROW(6) + y0], eb5 = em[NROW(6) + y1];
    float ea6 = em[NROW(7) + y0], eb6 = em[NROW(7) + y1];
    float ea7 = em[NROW(8) + y0], eb7 = em[NROW(8) + y1];

    for (int it = 0; it < 249; ++it) {
      const int s = 1 + it * 8;
      const float ta0 = ea0, tb0 = eb0, ta1 = ea1, tb1 = eb1;
      const float ta2 = ea2, tb2 = eb2, ta3 = ea3, tb3 = eb3;
      const float ta4 = ea4, tb4 = eb4, ta5 = ea5, tb5 = eb5;
      const float ta6 = ea6, tb6 = eb6, ta7 = ea7, tb7 = eb7;
      ea0 = em[NROW(s + 8)  + y0]; eb0 = em[NROW(s + 8)  + y1]; NSTEP(ta0, tb0);
      ea1 = em[NROW(s + 9)  + y0]; eb1 = em[NROW(s + 9)  + y1]; NSTEP(ta1, tb1);
      ea2 = em[NROW(s + 10) + y0]; eb2 = em[NROW(s + 10) + y1]; NSTEP(ta2, tb2);
      ea3 = em[NROW(s + 11) + y0]; eb3 = em[NROW(s + 11) + y1]; NSTEP(ta3, tb3);
      ea4 = em[NROW(s + 12) + y0]; eb4 = em[NROW(s + 12) + y1]; NSTEP(ta4, tb4);
      ea5 = em[NROW(s + 13) + y0]; eb5 = em[NROW(s + 13) + y1]; NSTEP(ta5, tb5);
      ea6 = em[NROW(s + 14) + y0]; eb6 = em[NROW(s + 14) + y1]; NSTEP(ta6, tb6);
      ea7 = em[NROW(s + 15) + y0]; eb7 = em[NROW(s + 15) + y1]; NSTEP(ta7, tb7);
    }
    NSTEP(ea0, eb0); NSTEP(ea1, eb1); NSTEP(ea2, eb2); NSTEP(ea3, eb3);
    NSTEP(ea4, eb4); NSTEP(ea5, eb5); NSTEP(ea6, eb6);
#undef NSTEP
#undef NROW

    if (v0) ws[(dir ? WS_HB : WS_NF) + b * 112 + 2 * l]     = b0;
    if (v1) ws[(dir ? WS_HB : WS_NF) + b * 112 + 2 * l + 1] = b1;
  }
}

__global__ __launch_bounds__(128) void asg_combine(
    const float* __restrict__ TR, const int* __restrict__ Y,
    const float* __restrict__ ws, float* __restrict__ lossv)
{
  const int b = blockIdx.x;
  const int tid = threadIdx.x;
  __shared__ float sA[NN], sG[NN], sN[LL], sH[LL], red[128];
  __shared__ float sLogZ;
  if (tid < NN) { sA[tid] = ws[WS_AF + b * NN + tid]; sG[tid] = ws[WS_GB + b * NN + tid]; }
  if (tid < LL) { sN[tid] = ws[WS_NF + b * 112 + tid]; sH[tid] = ws[WS_HB + b * 112 + tid]; }
  __syncthreads();

  float val = -3.0e38f;
  if (tid < NN) {
    const int i = tid;
    float m = -3.0e38f;
    for (int j = 0; j < NN; ++j) m = fmaxf(m, sA[j] + TR[(i + 1) * NN + j] * L2E);
    float s = 0.f;
    for (int j = 0; j < NN; ++j) s += exp2f(sA[j] + TR[(i + 1) * NN + j] * L2E - m);
    val = m + log2f(s) + sG[i];
  }
  red[tid] = val;
  __syncthreads();
  if (tid == 0) {
    float m = red[0];
    for (int k = 1; k < NN; ++k) m = fmaxf(m, red[k]);
    float s = 0.f;
    for (int k = 0; k < NN; ++k) s += exp2f(red[k] - m);
    sLogZ = m + log2f(s);
  }
  __syncthreads();

  float val2 = -3.0e38f;
  if (tid < LL) {
    const int l = tid;
    const int y = Y[b * LL + l];
    const float s1 = sN[l] + TR[(y + 1) * NN + y] * L2E;
    float s2 = NEG2;
    if (l > 0) {
      const int ymm = Y[b * LL + l - 1];
      s2 = sN[l - 1] + TR[(y + 1) * NN + ymm] * L2E;
    }
    const float m = fmaxf(s1, s2);
    val2 = m + log2f(exp2f(s1 - m) + exp2f(s2 - m)) + sH[l];
  }
  red[tid] = val2;
  __syncthreads();
  if (tid == 0) {
    float m = red[0];
    for (int k = 1; k < LL; ++k) m = fmaxf(m, red[k]);
    float s = 0.f;
    for (int k = 0; k < LL; ++k) s += exp2f(red[k] - m);
    const float tgt2 = m + log2f(s);
    lossv[b] = (sLogZ - tgt2) * LN2F / (float)LL;
  }
}

__global__ __launch_bounds__(64) void asg_reduce(const float* __restrict__ lossv,
                                                 float* __restrict__ out)
{
  const int tid = threadIdx.x;
  float v = lossv[tid] + lossv[tid + 64];
  for (int off = 32; off; off >>= 1) v += __shfl_xor(v, off);
  if (tid == 0) out[0] = v * (1.0f / 128.0f);
}

extern "C" void kernel_launch(void* const* d_in, const int* in_sizes, int n_in,
                              void* d_out, int out_size, void* d_ws, size_t ws_size,
                              hipStream_t stream) {
  const float* E  = (const float*)d_in[0];
  const float* TR = (const float*)d_in[1];
  const int*   Y  = (const int*)d_in[2];
  float* out = (float*)d_out;
  float* ws  = (float*)d_ws;
  float* lossv = ws + WS_LOSS;

  asg_main<<<dim3(256), dim3(128), 0, stream>>>(E, TR, Y, ws);
  asg_combine<<<dim3(128), dim3(128), 0, stream>>>(TR, Y, ws, lossv);
  asg_reduce<<<dim3(1), dim3(64), 0, stream>>>(lossv, out);
}

// Round 4
// 376.934 us; speedup vs baseline: 1.4136x; 1.1802x over previous
//
#include <hip/hip_runtime.h>

// ASG loss, B=128 T=4000 N=64 L=101.
// R4: overlap-and-discard segmented scan for the denominator.
//   The positive recurrence P' = D_t W P contracts in the Hilbert projective
//   metric (kappa ~ 0.3/step for this W), so each of NSEG=32 segments warms
//   up from a UNIFORM vector WARM=40 steps early (direction error ~1e-20),
//   then accumulates its exact log2-growth: X_s = log2(1^T a_end / 1^T a_start).
//   logZ = sum_s X_s (telescopes; segment 0 starts exactly from alpha_0).
//   Core per-step kernel is R2's verified single-wave fdot2/LDS matvec.
//   Numerator: R2's verified fwd/bwd log-domain chains (blocks 0..255,
//   launched first so they start immediately).

#define TT 4000
#define NN 64
#define LL 101
#define NSEG 32
#define SEGN 125          // steps per segment (last segment: 124)
#define WARM 40
#define NUMB 256          // numerator blocks

static constexpr float L2E  = 1.44269504088896340736f;   // log2(e)
static constexpr float LN2F = 0.69314718055994530942f;
static constexpr float NEG2 = -1.0e30f;

// ws layout (floats) - total ~132 KB
#define WS_X    0                      // [128][NSEG] per-segment log2 ratios
#define WS_NF   4096                   // [128][112] fwd numer (log2) at t=1999
#define WS_HB   18432                  // [128][112] bwd numer (log2) at t=2000
#define WS_LOSS 32768                  // [128] per-batch loss

#if defined(__has_builtin)
#if __has_builtin(__builtin_amdgcn_fdot2)
#define USE_FDOT2 1
#endif
#endif
#ifndef USE_FDOT2
#define USE_FDOT2 0
#endif

typedef _Float16 h2 __attribute__((ext_vector_type(2)));

__device__ __forceinline__ float wsum64(float v) {
  v += __shfl_xor(v, 1);  v += __shfl_xor(v, 2);  v += __shfl_xor(v, 4);
  v += __shfl_xor(v, 8);  v += __shfl_xor(v, 16); v += __shfl_xor(v, 32);
  return v;
}

__global__ __launch_bounds__(64) void asg_main(
    const float* __restrict__ E, const float* __restrict__ TR,
    const int* __restrict__ Y, float* __restrict__ ws)
{
  const int bid = blockIdx.x;
  const int tid = threadIdx.x;

#if USE_FDOT2
  __shared__ _Float16 PS[2][64];
#else
  __shared__ float PS[2][64];
#endif

  if (bid >= NUMB) {
    // ================= denominator segment (1 wave) =================
    const int db = bid - NUMB;
    const int b  = db >> 5;            // NSEG = 32
    const int s  = db & 31;
    const float* em = E + (size_t)b * TT * NN;
    const int i = tid;

#if USE_FDOT2
    h2 W2[32];
#pragma unroll
    for (int k = 0; k < 32; ++k) {
      const float w0 = TR[(i + 1) * NN + 2 * k];
      const float w1 = TR[(i + 1) * NN + 2 * k + 1];
      h2 t; t.x = (_Float16)exp2f(w0 * L2E); t.y = (_Float16)exp2f(w1 * L2E);
      W2[k] = t;
    }
#else
    const int h0 = (i >> 5) << 5;      // pair-split: states {i, i^32}
    const int ip = i ^ 32;
    float WA[32], WB[32];
#pragma unroll
    for (int k = 0; k < 32; ++k) {
      const int j = h0 + k;
      WA[k] = exp2f(TR[(i + 1) * NN + j] * L2E);
      WB[k] = exp2f(TR[(ip + 1) * NN + j] * L2E);
    }
#endif

    const int t0    = 1 + SEGN * s;
    const int nmain = (s == NSEG - 1) ? (TT - t0) : SEGN;
    float Pl, Csum;
    if (s == 0) {
      const float a0  = (em[i] + TR[i]) * L2E;
      const float a00 = __shfl(a0, 0);
      Csum = a00;
      Pl   = exp2f(a0 - a00);
    } else {
      Csum = 0.f;
      Pl   = 1.0f;
    }
#if USE_FDOT2
    PS[0][i] = (_Float16)Pl;
#else
    PS[0][i] = Pl;
#endif
    asm volatile("" ::: "memory");
    int buf = 0;

#define EML(t) em[(size_t)((t) < (TT - 1) ? (t) : (TT - 1)) * NN + i]

#if USE_FDOT2
#define BCH2(x) __builtin_bit_cast(h2, (x))
#define D4(u, k)                                                               \
    c0 = __builtin_amdgcn_fdot2(BCH2(u.x), W2[k], c0, false);                  \
    c1 = __builtin_amdgcn_fdot2(BCH2(u.y), W2[k + 1], c1, false);              \
    c2 = __builtin_amdgcn_fdot2(BCH2(u.z), W2[k + 2], c2, false);              \
    c3 = __builtin_amdgcn_fdot2(BCH2(u.w), W2[k + 3], c3, false);

#define DSTEP(EC)                                                              \
    {                                                                          \
      const uint4* pv = (const uint4*)&PS[buf][0];                             \
      const uint4 u0 = pv[0], u1 = pv[1], u2 = pv[2], u3 = pv[3];              \
      const uint4 u4 = pv[4], u5 = pv[5], u6 = pv[6], u7 = pv[7];              \
      float c0 = 0.f, c1 = 0.f, c2 = 0.f, c3 = 0.f;                            \
      D4(u0, 0)  D4(u1, 4)  D4(u2, 8)  D4(u3, 12)                              \
      D4(u4, 16) D4(u5, 20) D4(u6, 24) D4(u7, 28)                              \
      const float P0 = (float)BCH2(u0.x).x;                                    \
      const float S = (c0 + c1) + (c2 + c3);                                   \
      Pl = S * __builtin_amdgcn_rcpf(P0) * exp2f(fmaf((EC), L2E, -6.f));       \
      Csum += log2f(P0) + 6.f;                                                 \
      PS[buf ^ 1][i] = (_Float16)fminf(Pl, 60000.f);                           \
      asm volatile("" ::: "memory");                                           \
      buf ^= 1;                                                                \
    }
#else
#define F4(q, W_, k, acc)                                                      \
    acc = fmaf(q.x, W_[k], acc);     acc = fmaf(q.y, W_[k + 1], acc);          \
    acc = fmaf(q.z, W_[k + 2], acc); acc = fmaf(q.w, W_[k + 3], acc);

#define DSTEP(EC)                                                              \
    {                                                                          \
      const float4* pv = (const float4*)&PS[buf][h0];                          \
      const float4 q0 = pv[0], q1 = pv[1], q2 = pv[2], q3 = pv[3];             \
      const float4 q4 = pv[4], q5 = pv[5], q6 = pv[6], q7 = pv[7];             \
      const float P0 = PS[buf][0];                                             \
      float a0_ = 0.f, a1_ = 0.f, a2_ = 0.f, a3_ = 0.f;                        \
      float b0_ = 0.f, b1_ = 0.f, b2_ = 0.f, b3_ = 0.f;                        \
      F4(q0, WA, 0, a0_)  F4(q1, WA, 4, a1_)                                   \
      F4(q2, WA, 8, a2_)  F4(q3, WA, 12, a3_)                                  \
      F4(q4, WA, 16, a0_) F4(q5, WA, 20, a1_)                                  \
      F4(q6, WA, 24, a2_) F4(q7, WA, 28, a3_)                                  \
      F4(q0, WB, 0, b0_)  F4(q1, WB, 4, b1_)                                   \
      F4(q2, WB, 8, b2_)  F4(q3, WB, 12, b3_)                                  \
      F4(q4, WB, 16, b0_) F4(q5, WB, 20, b1_)                                  \
      F4(q6, WB, 24, b2_) F4(q7, WB, 28, b3_)                                  \
      const float SA = (a0_ + a1_) + (a2_ + a3_);                              \
      const float SB = (b0_ + b1_) + (b2_ + b3_);                              \
      const float S = SA + __shfl_xor(SB, 32);                                 \
      Pl = S * __builtin_amdgcn_rcpf(P0) * exp2f(fmaf((EC), L2E, -6.f));       \
      Csum += log2f(P0) + 6.f;                                                 \
      PS[buf ^ 1][i] = Pl;                                                     \
      asm volatile("" ::: "memory");                                           \
      buf ^= 1;                                                                \
    }
#endif

#define RUNPHASE(ts, te)                                                       \
    {                                                                          \
      int k_ = (ts);                                                           \
      float e0 = EML(k_), e1 = EML(k_ + 1), e2 = EML(k_ + 2), e3 = EML(k_ + 3);\
      for (; k_ + 4 <= (te); k_ += 4) {                                        \
        const float t0_ = e0, t1_ = e1, t2_ = e2, t3_ = e3;                    \
        e0 = EML(k_ + 4); DSTEP(t0_);                                          \
        e1 = EML(k_ + 5); DSTEP(t1_);                                          \
        e2 = EML(k_ + 6); DSTEP(t2_);                                          \
        e3 = EML(k_ + 7); DSTEP(t3_);                                          \
      }                                                                        \
      const int rem_ = (te) - k_;                                              \
      if (rem_ > 0) DSTEP(e0);                                                 \
      if (rem_ > 1) DSTEP(e1);                                                 \
      if (rem_ > 2) DSTEP(e2);                                                 \
    }

    float base = 0.f;
    if (s > 0) {
      RUNPHASE(t0 - WARM, t0);         // warm-up: direction converges
      base = Csum + log2f(wsum64(Pl)); // snapshot 1^T alpha at t0-1
    }
    RUNPHASE(t0, t0 + nmain);          // counted steps

    const float X = Csum + log2f(wsum64(Pl)) - base;
    if (i == 0) ws[WS_X + b * NSEG + s] = X;

#undef RUNPHASE
#undef DSTEP
#undef EML

  } else {
    // ================= numerator (R2-verified, log2 domain) =================
    const int b   = bid >> 1;
    const int dir = bid & 1;           // 0 = forward, 1 = backward
    const float* em = E + (size_t)b * TT * NN;
    const int l = tid;
    const bool v0 = (2 * l     <= 100);
    const bool v1 = (2 * l + 1 <= 100);
    const int k0 = v0 ? 2 * l     : 100;
    const int k1 = v1 ? 2 * l + 1 : 100;
    const int y0 = Y[b * LL + k0];
    const int y1 = Y[b * LL + k1];
    const float stw0 = TR[(y0 + 1) * NN + y0] * L2E;
    const float stw1 = TR[(y1 + 1) * NN + y1] * L2E;
    float aw0, aw1, b0, b1;
    if (dir == 0) {
      const int ym0 = Y[b * LL + (k0 > 0 ? k0 - 1 : 0)];
      aw0 = TR[(y0 + 1) * NN + ym0] * L2E;
      aw1 = TR[(y1 + 1) * NN + y0] * L2E;
      b0 = (k0 == 0) ? (TR[y0] + em[y0]) * L2E : NEG2;
      b1 = NEG2;
    } else {
      aw0 = TR[(y1 + 1) * NN + y0] * L2E;
      const int kp = (2 * l + 2 <= 100) ? 2 * l + 2 : 100;
      const int yp1 = Y[b * LL + kp];
      aw1 = TR[(yp1 + 1) * NN + y1] * L2E;
      b0 = em[(size_t)(TT - 1) * NN + y0] * L2E + ((k0 == 100) ? 0.f : NEG2);
      b1 = em[(size_t)(TT - 1) * NN + y1] * L2E + ((k1 == 100) ? 0.f : NEG2);
    }
    const bool pm0 = (dir == 0) ? (k0 > 0) : v1;
    const bool pm1 = (dir == 0) ? true : (2 * l + 2 <= 100);

#define NROW(s) ((size_t)((dir == 0) ? (s) : (TT - 1 - (s))) * NN)
#define NSTEP(EA, EB)                                                          \
    {                                                                          \
      const float ob0 = b0, ob1 = b1;                                          \
      const float nb = (dir == 0) ? __shfl_up(ob1, 1) : __shfl_down(ob0, 1);   \
      const float p0_ = pm0 ? ((dir == 0) ? nb : ob1) + aw0 : NEG2;            \
      const float p1_ = pm1 ? ((dir == 0) ? ob0 : nb) + aw1 : NEG2;            \
      const float x0 = ob0 + stw0, x1 = ob1 + stw1;                            \
      const float m0 = fmaxf(x0, p0_), m1 = fmaxf(x1, p1_);                    \
      b0 = m0 + log2f(exp2f(x0 - m0) + exp2f(p0_ - m0)) + (EA) * L2E;          \
      b1 = m1 + log2f(exp2f(x1 - m1) + exp2f(p1_ - m1)) + (EB) * L2E;          \
    }

    float ea0 = em[NROW(1) + y0], eb0 = em[NROW(1) + y1];
    float ea1 = em[NROW(2) + y0], eb1 = em[NROW(2) + y1];
    float ea2 = em[NROW(3) + y0], eb2 = em[NROW(3) + y1];
    float ea3 = em[NROW(4) + y0], eb3 = em[NROW(4) + y1];
    float ea4 = em[NROW(5) + y0], eb4 = em[NROW(5) + y1];
    float ea5 = em[NROW(6) + y0], eb5 = em[NROW(6) + y1];
    float ea6 = em[NROW(7) + y0], eb6 = em[NROW(7) + y1];
    float ea7 = em[NROW(8) + y0], eb7 = em[NROW(8) + y1];

    for (int it = 0; it < 249; ++it) {
      const int s = 1 + it * 8;
      const float ta0 = ea0, tb0 = eb0, ta1 = ea1, tb1 = eb1;
      const float ta2 = ea2, tb2 = eb2, ta3 = ea3, tb3 = eb3;
      const float ta4 = ea4, tb4 = eb4, ta5 = ea5, tb5 = eb5;
      const float ta6 = ea6, tb6 = eb6, ta7 = ea7, tb7 = eb7;
      ea0 = em[NROW(s + 8)  + y0]; eb0 = em[NROW(s + 8)  + y1]; NSTEP(ta0, tb0);
      ea1 = em[NROW(s + 9)  + y0]; eb1 = em[NROW(s + 9)  + y1]; NSTEP(ta1, tb1);
      ea2 = em[NROW(s + 10) + y0]; eb2 = em[NROW(s + 10) + y1]; NSTEP(ta2, tb2);
      ea3 = em[NROW(s + 11) + y0]; eb3 = em[NROW(s + 11) + y1]; NSTEP(ta3, tb3);
      ea4 = em[NROW(s + 12) + y0]; eb4 = em[NROW(s + 12) + y1]; NSTEP(ta4, tb4);
      ea5 = em[NROW(s + 13) + y0]; eb5 = em[NROW(s + 13) + y1]; NSTEP(ta5, tb5);
      ea6 = em[NROW(s + 14) + y0]; eb6 = em[NROW(s + 14) + y1]; NSTEP(ta6, tb6);
      ea7 = em[NROW(s + 15) + y0]; eb7 = em[NROW(s + 15) + y1]; NSTEP(ta7, tb7);
    }
    NSTEP(ea0, eb0); NSTEP(ea1, eb1); NSTEP(ea2, eb2); NSTEP(ea3, eb3);
    NSTEP(ea4, eb4); NSTEP(ea5, eb5); NSTEP(ea6, eb6);
#undef NSTEP
#undef NROW

    if (v0) ws[(dir ? WS_HB : WS_NF) + b * 112 + 2 * l]     = b0;
    if (v1) ws[(dir ? WS_HB : WS_NF) + b * 112 + 2 * l + 1] = b1;
  }
}

__global__ __launch_bounds__(128) void asg_combine(
    const float* __restrict__ TR, const int* __restrict__ Y,
    const float* __restrict__ ws, float* __restrict__ lossv)
{
  const int b = blockIdx.x;
  const int tid = threadIdx.x;
  __shared__ float sN[LL], sH[LL], red[128];
  __shared__ float sLogZ;

  if (tid == 0) {
    float z = 0.f;
    for (int s = 0; s < NSEG; ++s) z += ws[WS_X + b * NSEG + s];
    sLogZ = z;                              // log2(1^T alpha_{T-1}) = log2 Z
  }
  if (tid < LL) { sN[tid] = ws[WS_NF + b * 112 + tid]; sH[tid] = ws[WS_HB + b * 112 + tid]; }
  __syncthreads();

  // numerator bridge between fwd (t=1999) and bwd (t=2000)
  float val2 = -3.0e38f;
  if (tid < LL) {
    const int l = tid;
    const int y = Y[b * LL + l];
    const float s1 = sN[l] + TR[(y + 1) * NN + y] * L2E;
    float s2 = NEG2;
    if (l > 0) {
      const int ymm = Y[b * LL + l - 1];
      s2 = sN[l - 1] + TR[(y + 1) * NN + ymm] * L2E;
    }
    const float m = fmaxf(s1, s2);
    val2 = m + log2f(exp2f(s1 - m) + exp2f(s2 - m)) + sH[l];
  }
  red[tid] = val2;
  __syncthreads();
  if (tid == 0) {
    float m = red[0];
    for (int k = 1; k < LL; ++k) m = fmaxf(m, red[k]);
    float s = 0.f;
    for (int k = 0; k < LL; ++k) s += exp2f(red[k] - m);
    const float tgt2 = m + log2f(s);
    lossv[b] = (sLogZ - tgt2) * LN2F / (float)LL;
  }
}

__global__ __launch_bounds__(64) void asg_reduce(const float* __restrict__ lossv,
                                                 float* __restrict__ out)
{
  const int tid = threadIdx.x;
  float v = lossv[tid] + lossv[tid + 64];
  for (int off = 32; off; off >>= 1) v += __shfl_xor(v, off);
  if (tid == 0) out[0] = v * (1.0f / 128.0f);
}

extern "C" void kernel_launch(void* const* d_in, const int* in_sizes, int n_in,
                              void* d_out, int out_size, void* d_ws, size_t ws_size,
                              hipStream_t stream) {
  const float* E  = (const float*)d_in[0];
  const float* TR = (const float*)d_in[1];
  const int*   Y  = (const int*)d_in[2];
  float* out = (float*)d_out;
  float* ws  = (float*)d_ws;
  float* lossv = ws + WS_LOSS;

  asg_main<<<dim3(NUMB + 128 * NSEG), dim3(64), 0, stream>>>(E, TR, Y, ws);
  asg_combine<<<dim3(128), dim3(128), 0, stream>>>(TR, Y, ws, lossv);
  asg_reduce<<<dim3(1), dim3(64), 0, stream>>>(lossv, out);
}